// Round 6
// baseline (201.938 us; speedup 1.0000x reference)
//
#include <hip/hip_runtime.h>
#include <stdint.h>

#define NORI   197
#define FRAMES 8
#define NTOK   1576
#define BATCH  8
#define NHEAD  12
#define CDIM   768
#define MG     204
#define TOKENS 12608

typedef _Float16 half8 __attribute__((ext_vector_type(8)));
typedef float floatx4 __attribute__((ext_vector_type(4)));

typedef const __attribute__((address_space(1))) void GPTR;
typedef __attribute__((address_space(3))) void LPTR;

__device__ __forceinline__ int gather_idx(int m) {
    if (m < 8) return m * NORI;
    int u = m - 8;
    int f, t;
    if (u < 100) { f = u / 25; t = u - f * 25; }
    else         { f = 4 + (u - 100) / 24; t = (u - 100) - (f - 4) * 24; }
    return f * NORI + 1 + f + 8 * t;
}
__device__ __forceinline__ int col_frame(int m) {  // m in [8,204)
    int u = m - 8;
    return (u < 100) ? (u / 25) : (4 + (u - 100) / 24);
}

// ---------------- fused fp32 -> fp16 cast of x, qkv_w, proj_w ----------------
__global__ __launch_bounds__(256) void cast_all(
    const float* __restrict__ x, const float* __restrict__ qkvw,
    const float* __restrict__ projw, _Float16* __restrict__ out)
{
    const int n1 = TOKENS * CDIM / 8, n2 = 3 * CDIM * CDIM / 8, n3 = CDIM * CDIM / 8;
    int i = blockIdx.x * 256 + threadIdx.x;
    if (i >= n1 + n2 + n3) return;
    const float* src; int off;
    if (i < n1)           { src = x;     off = i; }
    else if (i < n1 + n2) { src = qkvw;  off = i - n1; }
    else                  { src = projw; off = i - n1 - n2; }
    float4 a = ((const float4*)src)[2 * off];
    float4 b = ((const float4*)src)[2 * off + 1];
    half8 o = { (_Float16)a.x, (_Float16)a.y, (_Float16)a.z, (_Float16)a.w,
                (_Float16)b.x, (_Float16)b.y, (_Float16)b.z, (_Float16)b.w };
    ((half8*)out)[i] = o;
}

// ---------------- MFMA GEMM body, BK=64: Y[r,c] = A[row(r),:] . W[Woff+c,:] ----------------
// 128x128 tile, BK=64 (12 K-iters, 32 MFMA/wave/iter), 4 waves (2x2 of 64x64).
// LDS layout: row-stride 64 halfs; chunk c of row r stored at pos c^(r&7).
// Staging: lane l -> row l>>3, pos l&7, global chunk (l&7)^((l>>3)&7);
// fragment reads hit 8 positions x 2 rows = 2-way bank alias (free).
template <int OUT_F32>
__device__ __forceinline__ void gemm_body(
    const _Float16* __restrict__ A, const _Float16* __restrict__ W,
    const float* __restrict__ bias, void* __restrict__ Y,
    int M, int Woff, int ldY, int gather, int r0, int c0,
    _Float16* As, _Float16* Bs)
{
    const int tid = threadIdx.x;
    const int w = tid >> 6, l = tid & 63;
    const int wm = (w >> 1) * 64, wn = (w & 1) * 64;

    const int pos = l & 7, rsub = l >> 3;
    const int cg = pos ^ rsub;               // swizzled global chunk

    const _Float16* sa[4];
    const _Float16* sb[4];
    _Float16* lA[4];
    _Float16* lB[4];
#pragma unroll
    for (int i = 0; i < 4; i++) {
        int rt = w * 32 + i * 8 + rsub;
        int ra = min(r0 + rt, M - 1);
        if (gather) { int b = ra / MG; int m = ra - b * MG; ra = b * NTOK + gather_idx(m); }
        sa[i] = A + (size_t)ra * CDIM + cg * 8;
        sb[i] = W + (size_t)(Woff + c0 + rt) * CDIM + cg * 8;
        lA[i] = &As[(w * 32 + i * 8) * 64];
        lB[i] = &Bs[(w * 32 + i * 8) * 64];
    }

    floatx4 acc[4][4] = {};
    const int mrow = l & 15, lq = l >> 4;

    for (int kb = 0; kb < CDIM; kb += 64) {
        __syncthreads();
#pragma unroll
        for (int i = 0; i < 4; i++) {
            __builtin_amdgcn_global_load_lds((GPTR*)(sa[i] + kb), (LPTR*)lA[i], 16, 0, 0);
            __builtin_amdgcn_global_load_lds((GPTR*)(sb[i] + kb), (LPTR*)lB[i], 16, 0, 0);
        }
        __syncthreads();

#pragma unroll
        for (int ksi = 0; ksi < 2; ksi++) {
            half8 af[4], bf[4];
#pragma unroll
            for (int t = 0; t < 4; t++) {
                af[t] = *(const half8*)&As[(wm + t * 16 + mrow) * 64 + (((ksi * 4 + lq)) ^ (mrow & 7)) * 8];
                bf[t] = *(const half8*)&Bs[(wn + t * 16 + mrow) * 64 + (((ksi * 4 + lq)) ^ (mrow & 7)) * 8];
            }
#pragma unroll
            for (int mt = 0; mt < 4; mt++)
#pragma unroll
                for (int nt = 0; nt < 4; nt++)
                    acc[mt][nt] = __builtin_amdgcn_mfma_f32_16x16x32_f16(af[mt], bf[nt], acc[mt][nt], 0, 0, 0);
        }
    }

#pragma unroll
    for (int nt = 0; nt < 4; nt++) {
        int col = c0 + wn + nt * 16 + (l & 15);
        float bv = bias ? bias[col] : 0.f;
#pragma unroll
        for (int mt = 0; mt < 4; mt++) {
#pragma unroll
            for (int r = 0; r < 4; r++) {
                int row = r0 + wm + mt * 16 + (l >> 4) * 4 + r;
                if (row < M) {
                    if (OUT_F32) ((float*)Y)[(size_t)row * ldY + col] = acc[mt][nt][r] + bv;
                    else ((_Float16*)Y)[(size_t)row * ldY + col] = (_Float16)acc[mt][nt][r];
                }
            }
        }
    }
}

// Q GEMM (594 blocks) + gathered-KV GEMM (156 blocks) in one dispatch
__global__ __launch_bounds__(256) void gemm_qkv(
    const _Float16* __restrict__ xh, const _Float16* __restrict__ qkvwh,
    _Float16* __restrict__ Qh, _Float16* __restrict__ KVh)
{
    __shared__ __align__(16) _Float16 As[128 * 64];
    __shared__ __align__(16) _Float16 Bs[128 * 64];
    int bx = blockIdx.x;
    if (bx < 594) {
        gemm_body<0>(xh, qkvwh, nullptr, Qh, TOKENS, 0, CDIM, 0,
                     (bx / 6) * 128, (bx % 6) * 128, As, Bs);
    } else {
        int b2 = bx - 594;
        gemm_body<0>(xh, qkvwh, nullptr, KVh, BATCH * MG, CDIM, 1536, 1,
                     (b2 / 12) * 128, (b2 % 12) * 128, As, Bs);
    }
}

__global__ __launch_bounds__(256) void gemm_proj(
    const _Float16* __restrict__ AOh, const _Float16* __restrict__ projwh,
    const float* __restrict__ bias, float* __restrict__ out)
{
    __shared__ __align__(16) _Float16 As[128 * 64];
    __shared__ __align__(16) _Float16 Bs[128 * 64];
    int bx = blockIdx.x;
    gemm_body<1>(AOh, projwh, bias, out, TOKENS, 0, CDIM, 0,
                 (bx / 6) * 128, (bx % 6) * 128, As, Bs);
}

// ---------------- fused masked attention, MFMA ----------------
// block = (b,h) x 320 q-rows (5 row-tiles of 16 per wave). K/V staged ONCE.
// LDS = 26112 (Ks, swizzled stride-64) + 26624 (Vt, stride 208) + 27648 (Ps)
//     = 80384 B <= 81920  ->  2 blocks/CU (8 waves).
__global__ __launch_bounds__(256, 2) void attn_mfma(
    const _Float16* __restrict__ Qh, const _Float16* __restrict__ KVh,
    _Float16* __restrict__ AOh)
{
    __shared__ __align__(16) _Float16 Ks[204 * 64];  // [row][chunk^(row&7)]
    __shared__ __align__(16) _Float16 Vt[64 * 208];
    __shared__ __align__(16) _Float16 Ps[64 * 216];  // wave w owns rows [w*16, +16)

    const int tid = threadIdx.x;
    const int bh = blockIdx.x;
    const int b = bh / NHEAD, h = bh - b * NHEAD;
    const int qc0 = blockIdx.y * 320;

    // ---- stage K, XOR-swizzled chunks (rows 204..207 unstaged; reads there
    //      land in Vt = finite garbage, fully masked by cf==-2) ----
    for (int e = tid; e < MG * 8; e += 256) {
        int row = e >> 3, c8 = e & 7;
        half8 v = *(const half8*)&KVh[(size_t)(b * MG + row) * 1536 + h * 64 + c8 * 8];
        *(half8*)&Ks[row * 64 + ((c8 ^ (row & 7)) * 8)] = v;
    }
    // ---- stage Vt [64 x 208] transposed ----
    {
        const int d0 = (tid >> 5) * 8, lmp = tid & 31;
#pragma unroll
        for (int mo = 0; mo < 7; mo++) {
            int mp = mo * 32 + lmp;
            if (mp >= 208) continue;
            half8 v = {};
            if (mp < MG) v = *(const half8*)&KVh[(size_t)(b * MG + mp) * 1536 + 768 + h * 64 + d0];
#pragma unroll
            for (int j = 0; j < 8; j++) Vt[(d0 + j) * 208 + mp] = v[j];
        }
    }
    __syncthreads();

    const int w = tid >> 6, l = tid & 63;
    const int lm = l & 15, lq = l >> 4;

    int cf[13];
#pragma unroll
    for (int t = 0; t < 13; t++) {
        int col = t * 16 + lm;
        cf[t] = (col < 8) ? -1 : (col >= MG ? -2 : col_frame(col));
    }

    _Float16* Pw = &Ps[(w * 16) * 216];

    for (int t5 = 0; t5 < 5; t5++) {
        const int rb = qc0 + t5 * 64 + w * 16;
        if (rb >= NTOK) break;   // per-wave exit; no barriers below

        // ---- QK^T: 16 q-rows vs 208 cols ----
        floatx4 acc[13] = {};
        const int qrowA = min(rb + lm, NTOK - 1);
        const _Float16* qbase = Qh + (size_t)(b * NTOK + qrowA) * CDIM + h * 64;
#pragma unroll
        for (int ks = 0; ks < 64; ks += 32) {
            half8 aq = *(const half8*)(qbase + ks + lq * 8);
#pragma unroll
            for (int t = 0; t < 13; t++) {
                half8 bk = *(const half8*)&Ks[(t * 16 + lm) * 64 + (((ks >> 3) + lq) ^ (lm & 7)) * 8];
                acc[t] = __builtin_amdgcn_mfma_f32_16x16x32_f16(aq, bk, acc[t], 0, 0, 0);
            }
        }

        // ---- masked softmax (rows lq*4 + r) ----
#pragma unroll
        for (int r = 0; r < 4; r++) {
            int qrow = min(rb + lq * 4 + r, NTOK - 1);
            int rf = qrow / NORI;
            float sv[13];
            float mx = -1e30f;
#pragma unroll
            for (int t = 0; t < 13; t++) {
                float s = acc[t][r] * 0.125f;
                s *= (cf[t] == -1 || cf[t] == rf) ? 1.f : 0.8f;
                if (cf[t] == -2) s = -1e30f;
                sv[t] = s;
                mx = fmaxf(mx, s);
            }
#pragma unroll
            for (int off = 1; off < 16; off <<= 1) mx = fmaxf(mx, __shfl_xor(mx, off, 64));
            float sum = 0.f;
#pragma unroll
            for (int t = 0; t < 13; t++) { sv[t] = __expf(sv[t] - mx); sum += sv[t]; }
#pragma unroll
            for (int off = 1; off < 16; off <<= 1) sum += __shfl_xor(sum, off, 64);
            float inv = 1.f / sum;
#pragma unroll
            for (int t = 0; t < 13; t++) acc[t][r] = sv[t] * inv;
        }

        // ---- P to per-wave LDS rows ----
#pragma unroll
        for (int t = 0; t < 13; t++)
#pragma unroll
            for (int r = 0; r < 4; r++)
                Pw[(lq * 4 + r) * 216 + t * 16 + lm] = (_Float16)acc[t][r];

        // ---- PV: O[16 x 64], k over 208 (cols 204..207: P=0, Vt=0) ----
        floatx4 oacc[4] = {};
        const _Float16* prow = &Pw[lm * 216];
#pragma unroll
        for (int ks = 0; ks < 192; ks += 32) {
            half8 ap = *(const half8*)(prow + ks + lq * 8);
#pragma unroll
            for (int t = 0; t < 4; t++) {
                half8 bv = *(const half8*)&Vt[(t * 16 + lm) * 208 + ks + lq * 8];
                oacc[t] = __builtin_amdgcn_mfma_f32_16x16x32_f16(ap, bv, oacc[t], 0, 0, 0);
            }
        }
        {   // K=16 tail (cols 192..207)
            typedef _Float16 half4v __attribute__((ext_vector_type(4)));
            half4v ap4 = *(const half4v*)(prow + 192 + lq * 4);
#pragma unroll
            for (int t = 0; t < 4; t++) {
                half4v bv4 = *(const half4v*)&Vt[(t * 16 + lm) * 208 + 192 + lq * 4];
                oacc[t] = __builtin_amdgcn_mfma_f32_16x16x16f16(ap4, bv4, oacc[t], 0, 0, 0);
            }
        }

#pragma unroll
        for (int t = 0; t < 4; t++)
#pragma unroll
            for (int r = 0; r < 4; r++) {
                int qrow = rb + lq * 4 + r;
                if (qrow < NTOK)
                    AOh[(size_t)(b * NTOK + qrow) * CDIM + h * 64 + t * 16 + lm] = (_Float16)oacc[t][r];
            }
    }
}

extern "C" void kernel_launch(void* const* d_in, const int* in_sizes, int n_in,
                              void* d_out, int out_size, void* d_ws, size_t ws_size,
                              hipStream_t stream) {
    const float* x      = (const float*)d_in[0];
    const float* qkv_w  = (const float*)d_in[1];
    const float* proj_w = (const float*)d_in[2];
    const float* proj_b = (const float*)d_in[3];
    float* out = (float*)d_out;

    _Float16* xh     = (_Float16*)d_ws;
    _Float16* qkvwh  = xh + (size_t)TOKENS * CDIM;
    _Float16* projwh = qkvwh + (size_t)3 * CDIM * CDIM;
    _Float16* Qh     = projwh + (size_t)CDIM * CDIM;
    _Float16* KVh    = Qh + (size_t)TOKENS * CDIM;
    _Float16* AOh    = KVh + (size_t)(BATCH * MG) * 1536;

    dim3 blk(256);
    const int ncast = (TOKENS * CDIM + 3 * CDIM * CDIM + CDIM * CDIM) / 8;
    cast_all<<<dim3((ncast + 255) / 256), blk, 0, stream>>>(x, qkv_w, proj_w, xh);

    gemm_qkv<<<dim3(594 + 156), blk, 0, stream>>>(xh, qkvwh, Qh, KVh);

    attn_mfma<<<dim3(BATCH * NHEAD, 5), blk, 0, stream>>>(Qh, KVh, AOh);

    gemm_proj<<<dim3(594), blk, 0, stream>>>(AOh, projwh, proj_b, out);
}

// Round 7
// 191.377 us; speedup vs baseline: 1.0552x; 1.0552x over previous
//
#include <hip/hip_runtime.h>
#include <stdint.h>

#define NORI   197
#define FRAMES 8
#define NTOK   1576
#define BATCH  8
#define NHEAD  12
#define CDIM   768
#define MG     204
#define TOKENS 12608

typedef _Float16 half8 __attribute__((ext_vector_type(8)));
typedef float floatx4 __attribute__((ext_vector_type(4)));

typedef const __attribute__((address_space(1))) void GPTR;
typedef __attribute__((address_space(3))) void LPTR;

__device__ __forceinline__ int gather_idx(int m) {
    if (m < 8) return m * NORI;
    int u = m - 8;
    int f, t;
    if (u < 100) { f = u / 25; t = u - f * 25; }
    else         { f = 4 + (u - 100) / 24; t = (u - 100) - (f - 4) * 24; }
    return f * NORI + 1 + f + 8 * t;
}
__device__ __forceinline__ int col_frame(int m) {  // m in [8,204)
    int u = m - 8;
    return (u < 100) ? (u / 25) : (4 + (u - 100) / 24);
}

// ---------------- fused fp32 -> fp16 cast of x, qkv_w, proj_w ----------------
__global__ __launch_bounds__(256) void cast_all(
    const float* __restrict__ x, const float* __restrict__ qkvw,
    const float* __restrict__ projw, _Float16* __restrict__ out)
{
    const int n1 = TOKENS * CDIM / 8, n2 = 3 * CDIM * CDIM / 8, n3 = CDIM * CDIM / 8;
    int i = blockIdx.x * 256 + threadIdx.x;
    if (i >= n1 + n2 + n3) return;
    const float* src; int off;
    if (i < n1)           { src = x;     off = i; }
    else if (i < n1 + n2) { src = qkvw;  off = i - n1; }
    else                  { src = projw; off = i - n1 - n2; }
    float4 a = ((const float4*)src)[2 * off];
    float4 b = ((const float4*)src)[2 * off + 1];
    half8 o = { (_Float16)a.x, (_Float16)a.y, (_Float16)a.z, (_Float16)a.w,
                (_Float16)b.x, (_Float16)b.y, (_Float16)b.z, (_Float16)b.w };
    ((half8*)out)[i] = o;
}

// ---------------- MFMA GEMM body, BK=64, double-buffered K-loop ----------------
// Per iter: issue next tile's loads into buf B, s_waitcnt vmcnt(8) lgkm(0)
// (own current-tile loads retired), raw s_barrier (collectively staged),
// compute buf A, raw s_barrier (release A for overwrite). Prefetch stays in
// flight across the barrier — no vmcnt(0) drain.
// LDS layout: row-stride 64 halfs; chunk c of row r stored at pos c^(r&7)
// (implicit via global-side swizzle); fragment reads 2-way bank alias (free).
template <int OUT_F32>
__device__ __forceinline__ void gemm_body(
    const _Float16* __restrict__ A, const _Float16* __restrict__ W,
    const float* __restrict__ bias, void* __restrict__ Y,
    int M, int Woff, int ldY, int gather, int r0, int c0,
    _Float16* As0, _Float16* Bs0, _Float16* As1, _Float16* Bs1)
{
    const int tid = threadIdx.x;
    const int w = tid >> 6, l = tid & 63;
    const int wm = (w >> 1) * 64, wn = (w & 1) * 64;

    const int pos = l & 7, rsub = l >> 3;
    const int cg = pos ^ rsub;               // swizzled global chunk

    const _Float16* sa[4];
    const _Float16* sb[4];
    int soff[4];
#pragma unroll
    for (int i = 0; i < 4; i++) {
        int rt = w * 32 + i * 8 + rsub;
        int ra = min(r0 + rt, M - 1);
        if (gather) { int b = ra / MG; int m = ra - b * MG; ra = b * NTOK + gather_idx(m); }
        sa[i] = A + (size_t)ra * CDIM + cg * 8;
        sb[i] = W + (size_t)(Woff + c0 + rt) * CDIM + cg * 8;
        soff[i] = (w * 32 + i * 8) * 64;
    }

    // prologue: stage tile 0 into buf0
#pragma unroll
    for (int i = 0; i < 4; i++) {
        __builtin_amdgcn_global_load_lds((GPTR*)sa[i], (LPTR*)(As0 + soff[i]), 16, 0, 0);
        __builtin_amdgcn_global_load_lds((GPTR*)sb[i], (LPTR*)(Bs0 + soff[i]), 16, 0, 0);
    }

    floatx4 acc[4][4] = {};
    const int mrow = l & 15, lq = l >> 4;

#pragma unroll
    for (int it = 0; it < 12; it++) {
        const _Float16* Ac = (it & 1) ? As1 : As0;
        const _Float16* Bc = (it & 1) ? Bs1 : Bs0;
        _Float16* An = (it & 1) ? As0 : As1;
        _Float16* Bn = (it & 1) ? Bs0 : Bs1;

        if (it < 11) {
            int kb = (it + 1) * 64;
#pragma unroll
            for (int i = 0; i < 4; i++) {
                __builtin_amdgcn_global_load_lds((GPTR*)(sa[i] + kb), (LPTR*)(An + soff[i]), 16, 0, 0);
                __builtin_amdgcn_global_load_lds((GPTR*)(sb[i] + kb), (LPTR*)(Bn + soff[i]), 16, 0, 0);
            }
            __builtin_amdgcn_s_waitcnt(0x0078);   // vmcnt(8) expcnt(7) lgkmcnt(0)
        } else {
            __builtin_amdgcn_s_waitcnt(0x0070);   // vmcnt(0) lgkmcnt(0)
        }
        __builtin_amdgcn_s_barrier();             // buf 'cur' collectively staged

#pragma unroll
        for (int ksi = 0; ksi < 2; ksi++) {
            half8 af[4], bf[4];
#pragma unroll
            for (int t = 0; t < 4; t++) {
                af[t] = *(const half8*)&Ac[(wm + t * 16 + mrow) * 64 + ((ksi * 4 + lq) ^ (mrow & 7)) * 8];
                bf[t] = *(const half8*)&Bc[(wn + t * 16 + mrow) * 64 + ((ksi * 4 + lq) ^ (mrow & 7)) * 8];
            }
#pragma unroll
            for (int mt = 0; mt < 4; mt++)
#pragma unroll
                for (int nt = 0; nt < 4; nt++)
                    acc[mt][nt] = __builtin_amdgcn_mfma_f32_16x16x32_f16(af[mt], bf[nt], acc[mt][nt], 0, 0, 0);
        }
        __builtin_amdgcn_s_barrier();             // release 'cur' for overwrite
    }

#pragma unroll
    for (int nt = 0; nt < 4; nt++) {
        int col = c0 + wn + nt * 16 + (l & 15);
        float bv = bias ? bias[col] : 0.f;
#pragma unroll
        for (int mt = 0; mt < 4; mt++) {
#pragma unroll
            for (int r = 0; r < 4; r++) {
                int row = r0 + wm + mt * 16 + (l >> 4) * 4 + r;
                if (row < M) {
                    if (OUT_F32) ((float*)Y)[(size_t)row * ldY + col] = acc[mt][nt][r] + bv;
                    else ((_Float16*)Y)[(size_t)row * ldY + col] = (_Float16)acc[mt][nt][r];
                }
            }
        }
    }
}

// XCD-grouping remap: all 6 col-blocks of row-block rb get bx === rb (mod 8),
// so they land on one XCD (heuristic: consecutive wg -> round-robin XCD).
// bx in [0, 624): xcd = bx&7, j = bx>>3; rb = (j%13)*8 + xcd; cb = j/13.
__device__ __forceinline__ bool xcd_map(int bx, int nrb, int& rb, int& cb) {
    int xcd = bx & 7, j = bx >> 3;
    rb = (j % 13) * 8 + xcd;
    cb = j / 13;
    return rb < nrb;
}

// Q GEMM (624 padded blocks) + gathered-KV GEMM (156 blocks) in one dispatch
__global__ __launch_bounds__(256) void gemm_qkv(
    const _Float16* __restrict__ xh, const _Float16* __restrict__ qkvwh,
    _Float16* __restrict__ Qh, _Float16* __restrict__ KVh)
{
    __shared__ __align__(16) _Float16 As0[128 * 64];
    __shared__ __align__(16) _Float16 Bs0[128 * 64];
    __shared__ __align__(16) _Float16 As1[128 * 64];
    __shared__ __align__(16) _Float16 Bs1[128 * 64];
    int bx = blockIdx.x;
    if (bx < 624) {
        int rb, cb;
        if (!xcd_map(bx, 99, rb, cb)) return;
        gemm_body<0>(xh, qkvwh, nullptr, Qh, TOKENS, 0, CDIM, 0,
                     rb * 128, cb * 128, As0, Bs0, As1, Bs1);
    } else {
        int b2 = bx - 624;
        gemm_body<0>(xh, qkvwh, nullptr, KVh, BATCH * MG, CDIM, 1536, 1,
                     (b2 / 12) * 128, (b2 % 12) * 128, As0, Bs0, As1, Bs1);
    }
}

__global__ __launch_bounds__(256) void gemm_proj(
    const _Float16* __restrict__ AOh, const _Float16* __restrict__ projwh,
    const float* __restrict__ bias, float* __restrict__ out)
{
    __shared__ __align__(16) _Float16 As0[128 * 64];
    __shared__ __align__(16) _Float16 Bs0[128 * 64];
    __shared__ __align__(16) _Float16 As1[128 * 64];
    __shared__ __align__(16) _Float16 Bs1[128 * 64];
    int rb, cb;
    if (!xcd_map(blockIdx.x, 99, rb, cb)) return;
    gemm_body<1>(AOh, projwh, bias, out, TOKENS, 0, CDIM, 0,
                 rb * 128, cb * 128, As0, Bs0, As1, Bs1);
}

// ---------------- fused masked attention, MFMA ----------------
// block = (b,h) x 320 q-rows (5 row-tiles of 16 per wave). K/V staged ONCE.
// LDS = 26112 + 26624 + 27648 = 80384 B <= 81920 -> 2 blocks/CU.
__global__ __launch_bounds__(256, 2) void attn_mfma(
    const _Float16* __restrict__ Qh, const _Float16* __restrict__ KVh,
    _Float16* __restrict__ AOh)
{
    __shared__ __align__(16) _Float16 Ks[204 * 64];  // [row][chunk^(row&7)]
    __shared__ __align__(16) _Float16 Vt[64 * 208];
    __shared__ __align__(16) _Float16 Ps[64 * 216];  // wave w owns rows [w*16, +16)

    const int tid = threadIdx.x;
    const int bh = blockIdx.x;
    const int b = bh / NHEAD, h = bh - b * NHEAD;
    const int qc0 = blockIdx.y * 320;

    for (int e = tid; e < MG * 8; e += 256) {
        int row = e >> 3, c8 = e & 7;
        half8 v = *(const half8*)&KVh[(size_t)(b * MG + row) * 1536 + h * 64 + c8 * 8];
        *(half8*)&Ks[row * 64 + ((c8 ^ (row & 7)) * 8)] = v;
    }
    {
        const int d0 = (tid >> 5) * 8, lmp = tid & 31;
#pragma unroll
        for (int mo = 0; mo < 7; mo++) {
            int mp = mo * 32 + lmp;
            if (mp >= 208) continue;
            half8 v = {};
            if (mp < MG) v = *(const half8*)&KVh[(size_t)(b * MG + mp) * 1536 + 768 + h * 64 + d0];
#pragma unroll
            for (int j = 0; j < 8; j++) Vt[(d0 + j) * 208 + mp] = v[j];
        }
    }
    __syncthreads();

    const int w = tid >> 6, l = tid & 63;
    const int lm = l & 15, lq = l >> 4;

    int cf[13];
#pragma unroll
    for (int t = 0; t < 13; t++) {
        int col = t * 16 + lm;
        cf[t] = (col < 8) ? -1 : (col >= MG ? -2 : col_frame(col));
    }

    _Float16* Pw = &Ps[(w * 16) * 216];

    for (int t5 = 0; t5 < 5; t5++) {
        const int rb = qc0 + t5 * 64 + w * 16;
        if (rb >= NTOK) break;   // per-wave exit; no barriers below

        floatx4 acc[13] = {};
        const int qrowA = min(rb + lm, NTOK - 1);
        const _Float16* qbase = Qh + (size_t)(b * NTOK + qrowA) * CDIM + h * 64;
#pragma unroll
        for (int ks = 0; ks < 64; ks += 32) {
            half8 aq = *(const half8*)(qbase + ks + lq * 8);
#pragma unroll
            for (int t = 0; t < 13; t++) {
                half8 bk = *(const half8*)&Ks[(t * 16 + lm) * 64 + (((ks >> 3) + lq) ^ (lm & 7)) * 8];
                acc[t] = __builtin_amdgcn_mfma_f32_16x16x32_f16(aq, bk, acc[t], 0, 0, 0);
            }
        }

#pragma unroll
        for (int r = 0; r < 4; r++) {
            int qrow = min(rb + lq * 4 + r, NTOK - 1);
            int rf = qrow / NORI;
            float sv[13];
            float mx = -1e30f;
#pragma unroll
            for (int t = 0; t < 13; t++) {
                float s = acc[t][r] * 0.125f;
                s *= (cf[t] == -1 || cf[t] == rf) ? 1.f : 0.8f;
                if (cf[t] == -2) s = -1e30f;
                sv[t] = s;
                mx = fmaxf(mx, s);
            }
#pragma unroll
            for (int off = 1; off < 16; off <<= 1) mx = fmaxf(mx, __shfl_xor(mx, off, 64));
            float sum = 0.f;
#pragma unroll
            for (int t = 0; t < 13; t++) { sv[t] = __expf(sv[t] - mx); sum += sv[t]; }
#pragma unroll
            for (int off = 1; off < 16; off <<= 1) sum += __shfl_xor(sum, off, 64);
            float inv = 1.f / sum;
#pragma unroll
            for (int t = 0; t < 13; t++) acc[t][r] = sv[t] * inv;
        }

#pragma unroll
        for (int t = 0; t < 13; t++)
#pragma unroll
            for (int r = 0; r < 4; r++)
                Pw[(lq * 4 + r) * 216 + t * 16 + lm] = (_Float16)acc[t][r];

        floatx4 oacc[4] = {};
        const _Float16* prow = &Pw[lm * 216];
#pragma unroll
        for (int ks = 0; ks < 192; ks += 32) {
            half8 ap = *(const half8*)(prow + ks + lq * 8);
#pragma unroll
            for (int t = 0; t < 4; t++) {
                half8 bv = *(const half8*)&Vt[(t * 16 + lm) * 208 + ks + lq * 8];
                oacc[t] = __builtin_amdgcn_mfma_f32_16x16x32_f16(ap, bv, oacc[t], 0, 0, 0);
            }
        }
        {
            typedef _Float16 half4v __attribute__((ext_vector_type(4)));
            half4v ap4 = *(const half4v*)(prow + 192 + lq * 4);
#pragma unroll
            for (int t = 0; t < 4; t++) {
                half4v bv4 = *(const half4v*)&Vt[(t * 16 + lm) * 208 + 192 + lq * 4];
                oacc[t] = __builtin_amdgcn_mfma_f32_16x16x16f16(ap4, bv4, oacc[t], 0, 0, 0);
            }
        }

#pragma unroll
        for (int t = 0; t < 4; t++)
#pragma unroll
            for (int r = 0; r < 4; r++) {
                int qrow = rb + lq * 4 + r;
                if (qrow < NTOK)
                    AOh[(size_t)(b * NTOK + qrow) * CDIM + h * 64 + t * 16 + lm] = (_Float16)oacc[t][r];
            }
    }
}

extern "C" void kernel_launch(void* const* d_in, const int* in_sizes, int n_in,
                              void* d_out, int out_size, void* d_ws, size_t ws_size,
                              hipStream_t stream) {
    const float* x      = (const float*)d_in[0];
    const float* qkv_w  = (const float*)d_in[1];
    const float* proj_w = (const float*)d_in[2];
    const float* proj_b = (const float*)d_in[3];
    float* out = (float*)d_out;

    _Float16* xh     = (_Float16*)d_ws;
    _Float16* qkvwh  = xh + (size_t)TOKENS * CDIM;
    _Float16* projwh = qkvwh + (size_t)3 * CDIM * CDIM;
    _Float16* Qh     = projwh + (size_t)CDIM * CDIM;
    _Float16* KVh    = Qh + (size_t)TOKENS * CDIM;
    _Float16* AOh    = KVh + (size_t)(BATCH * MG) * 1536;

    dim3 blk(256);
    const int ncast = (TOKENS * CDIM + 3 * CDIM * CDIM + CDIM * CDIM) / 8;
    cast_all<<<dim3((ncast + 255) / 256), blk, 0, stream>>>(x, qkv_w, proj_w, xh);

    gemm_qkv<<<dim3(624 + 156), blk, 0, stream>>>(xh, qkvwh, Qh, KVh);

    attn_mfma<<<dim3(BATCH * NHEAD, 5), blk, 0, stream>>>(Qh, KVh, AOh);

    gemm_proj<<<dim3(624), blk, 0, stream>>>(AOh, projwh, proj_b, out);
}

// Round 8
// 187.925 us; speedup vs baseline: 1.0746x; 1.0184x over previous
//
#include <hip/hip_runtime.h>
#include <stdint.h>

#define NORI   197
#define FRAMES 8
#define NTOK   1576
#define BATCH  8
#define NHEAD  12
#define CDIM   768
#define MG     204
#define TOKENS 12608

typedef _Float16 half8 __attribute__((ext_vector_type(8)));
typedef float floatx4 __attribute__((ext_vector_type(4)));

typedef const __attribute__((address_space(1))) void GPTR;
typedef __attribute__((address_space(3))) void LPTR;

__device__ __forceinline__ int gather_idx(int m) {
    if (m < 8) return m * NORI;
    int u = m - 8;
    int f, t;
    if (u < 100) { f = u / 25; t = u - f * 25; }
    else         { f = 4 + (u - 100) / 24; t = (u - 100) - (f - 4) * 24; }
    return f * NORI + 1 + f + 8 * t;
}
__device__ __forceinline__ int col_frame(int m) {  // m in [8,204)
    int u = m - 8;
    return (u < 100) ? (u / 25) : (4 + (u - 100) / 24);
}

// ---------------- fused fp32 -> fp16 cast of x, qkv_w, proj_w ----------------
__global__ __launch_bounds__(256) void cast_all(
    const float* __restrict__ x, const float* __restrict__ qkvw,
    const float* __restrict__ projw, _Float16* __restrict__ out)
{
    const int n1 = TOKENS * CDIM / 8, n2 = 3 * CDIM * CDIM / 8, n3 = CDIM * CDIM / 8;
    int i = blockIdx.x * 256 + threadIdx.x;
    if (i >= n1 + n2 + n3) return;
    const float* src; int off;
    if (i < n1)           { src = x;     off = i; }
    else if (i < n1 + n2) { src = qkvw;  off = i - n1; }
    else                  { src = projw; off = i - n1 - n2; }
    float4 a = ((const float4*)src)[2 * off];
    float4 b = ((const float4*)src)[2 * off + 1];
    half8 o = { (_Float16)a.x, (_Float16)a.y, (_Float16)a.z, (_Float16)a.w,
                (_Float16)b.x, (_Float16)b.y, (_Float16)b.z, (_Float16)b.w };
    ((half8*)out)[i] = o;
}

// ---------------- MFMA GEMM body, BK=32, double-buffered, 32 KB LDS ----------------
// Per iter: issue next tile's 4 loads into buf B, s_waitcnt vmcnt(4) lgkm(0)
// (own current-tile loads retired), raw s_barrier, compute 16 MFMA from buf A,
// raw s_barrier. Prefetch stays in flight across the barrier; 32 KB total LDS
// keeps 4-5 blocks/CU so the grid packs in ~1 round.
// LDS: row = 32 halfs (4 chunks of 16 B); chunk swizzle on the global side,
// fragment reads 2-way bank alias (0 conflicts measured R5).
template <int OUT_F32>
__device__ __forceinline__ void gemm_body(
    const _Float16* __restrict__ A, const _Float16* __restrict__ W,
    const float* __restrict__ bias, void* __restrict__ Y,
    int M, int Woff, int ldY, int gather, int r0, int c0,
    _Float16* As0, _Float16* Bs0, _Float16* As1, _Float16* Bs1)
{
    const int tid = threadIdx.x;
    const int w = tid >> 6, l = tid & 63;
    const int wm = (w >> 1) * 64, wn = (w & 1) * 64;

    const _Float16* sa[2];
    const _Float16* sb[2];
    int soff[2];
#pragma unroll
    for (int i = 0; i < 2; i++) {
        int rt = w * 32 + i * 16 + (l >> 2);
        int cg = (l & 3) ^ ((l >> 3) & 3);       // swizzled global chunk
        int ra = min(r0 + rt, M - 1);
        if (gather) { int b = ra / MG; int m = ra - b * MG; ra = b * NTOK + gather_idx(m); }
        sa[i] = A + (size_t)ra * CDIM + cg * 8;
        sb[i] = W + (size_t)(Woff + c0 + rt) * CDIM + cg * 8;
        soff[i] = (w * 32 + i * 16) * 32;
    }

    // prologue: stage tile 0 into buf0
#pragma unroll
    for (int i = 0; i < 2; i++) {
        __builtin_amdgcn_global_load_lds((GPTR*)sa[i], (LPTR*)(As0 + soff[i]), 16, 0, 0);
        __builtin_amdgcn_global_load_lds((GPTR*)sb[i], (LPTR*)(Bs0 + soff[i]), 16, 0, 0);
    }

    floatx4 acc[4][4] = {};
    const int fc = ((l >> 4) ^ ((l >> 1) & 3)) * 8;
    const int mrow = l & 15;

#pragma unroll
    for (int it = 0; it < 24; it++) {
        const _Float16* Ac = (it & 1) ? As1 : As0;
        const _Float16* Bc = (it & 1) ? Bs1 : Bs0;
        _Float16* An = (it & 1) ? As0 : As1;
        _Float16* Bn = (it & 1) ? Bs0 : Bs1;

        if (it < 23) {
            int kb = (it + 1) * 32;
#pragma unroll
            for (int i = 0; i < 2; i++) {
                __builtin_amdgcn_global_load_lds((GPTR*)(sa[i] + kb), (LPTR*)(An + soff[i]), 16, 0, 0);
                __builtin_amdgcn_global_load_lds((GPTR*)(sb[i] + kb), (LPTR*)(Bn + soff[i]), 16, 0, 0);
            }
            __builtin_amdgcn_s_waitcnt(0x0074);   // vmcnt(4) expcnt(7) lgkmcnt(0)
        } else {
            __builtin_amdgcn_s_waitcnt(0x0070);   // vmcnt(0) lgkmcnt(0)
        }
        __builtin_amdgcn_s_barrier();             // buf 'cur' collectively staged

        half8 af[4], bf[4];
#pragma unroll
        for (int t = 0; t < 4; t++) {
            af[t] = *(const half8*)&Ac[(wm + t * 16 + mrow) * 32 + fc];
            bf[t] = *(const half8*)&Bc[(wn + t * 16 + mrow) * 32 + fc];
        }
#pragma unroll
        for (int mt = 0; mt < 4; mt++)
#pragma unroll
            for (int nt = 0; nt < 4; nt++)
                acc[mt][nt] = __builtin_amdgcn_mfma_f32_16x16x32_f16(af[mt], bf[nt], acc[mt][nt], 0, 0, 0);

        __builtin_amdgcn_s_barrier();             // release 'cur' for overwrite
    }

#pragma unroll
    for (int nt = 0; nt < 4; nt++) {
        int col = c0 + wn + nt * 16 + (l & 15);
        float bv = bias ? bias[col] : 0.f;
#pragma unroll
        for (int mt = 0; mt < 4; mt++) {
#pragma unroll
            for (int r = 0; r < 4; r++) {
                int row = r0 + wm + mt * 16 + (l >> 4) * 4 + r;
                if (row < M) {
                    if (OUT_F32) ((float*)Y)[(size_t)row * ldY + col] = acc[mt][nt][r] + bv;
                    else ((_Float16*)Y)[(size_t)row * ldY + col] = (_Float16)acc[mt][nt][r];
                }
            }
        }
    }
}

// XCD-grouping remap: all 6 col-blocks of row-block rb get bx === rb (mod 8),
// so they land on one XCD. bx in [0,624): xcd = bx&7, j = bx>>3;
// rb = (j%13)*8 + xcd; cb = j/13. Dummies (rb >= 99) exit immediately.
__device__ __forceinline__ bool xcd_map(int bx, int nrb, int& rb, int& cb) {
    int xcd = bx & 7, j = bx >> 3;
    rb = (j % 13) * 8 + xcd;
    cb = j / 13;
    return rb < nrb;
}

// Q GEMM (624 padded blocks) + gathered-KV GEMM (156 blocks) in one dispatch
__global__ __launch_bounds__(256) void gemm_qkv(
    const _Float16* __restrict__ xh, const _Float16* __restrict__ qkvwh,
    _Float16* __restrict__ Qh, _Float16* __restrict__ KVh)
{
    __shared__ __align__(16) _Float16 As0[128 * 32];
    __shared__ __align__(16) _Float16 Bs0[128 * 32];
    __shared__ __align__(16) _Float16 As1[128 * 32];
    __shared__ __align__(16) _Float16 Bs1[128 * 32];
    int bx = blockIdx.x;
    if (bx < 624) {
        int rb, cb;
        if (!xcd_map(bx, 99, rb, cb)) return;
        gemm_body<0>(xh, qkvwh, nullptr, Qh, TOKENS, 0, CDIM, 0,
                     rb * 128, cb * 128, As0, Bs0, As1, Bs1);
    } else {
        int b2 = bx - 624;
        gemm_body<0>(xh, qkvwh, nullptr, KVh, BATCH * MG, CDIM, 1536, 1,
                     (b2 / 12) * 128, (b2 % 12) * 128, As0, Bs0, As1, Bs1);
    }
}

__global__ __launch_bounds__(256) void gemm_proj(
    const _Float16* __restrict__ AOh, const _Float16* __restrict__ projwh,
    const float* __restrict__ bias, float* __restrict__ out)
{
    __shared__ __align__(16) _Float16 As0[128 * 32];
    __shared__ __align__(16) _Float16 Bs0[128 * 32];
    __shared__ __align__(16) _Float16 As1[128 * 32];
    __shared__ __align__(16) _Float16 Bs1[128 * 32];
    int rb, cb;
    if (!xcd_map(blockIdx.x, 99, rb, cb)) return;
    gemm_body<1>(AOh, projwh, bias, out, TOKENS, 0, CDIM, 0,
                 rb * 128, cb * 128, As0, Bs0, As1, Bs1);
}

// ---------------- fused masked attention, MFMA ----------------
// block = (b,h) x 320 q-rows (5 row-tiles of 16 per wave). K/V staged ONCE.
// LDS = 26112 + 26624 + 27648 = 80384 B <= 81920 -> 2 blocks/CU.
__global__ __launch_bounds__(256, 2) void attn_mfma(
    const _Float16* __restrict__ Qh, const _Float16* __restrict__ KVh,
    _Float16* __restrict__ AOh)
{
    __shared__ __align__(16) _Float16 Ks[204 * 64];  // [row][chunk^(row&7)]
    __shared__ __align__(16) _Float16 Vt[64 * 208];
    __shared__ __align__(16) _Float16 Ps[64 * 216];  // wave w owns rows [w*16, +16)

    const int tid = threadIdx.x;
    const int bh = blockIdx.x;
    const int b = bh / NHEAD, h = bh - b * NHEAD;
    const int qc0 = blockIdx.y * 320;

    for (int e = tid; e < MG * 8; e += 256) {
        int row = e >> 3, c8 = e & 7;
        half8 v = *(const half8*)&KVh[(size_t)(b * MG + row) * 1536 + h * 64 + c8 * 8];
        *(half8*)&Ks[row * 64 + ((c8 ^ (row & 7)) * 8)] = v;
    }
    {
        const int d0 = (tid >> 5) * 8, lmp = tid & 31;
#pragma unroll
        for (int mo = 0; mo < 7; mo++) {
            int mp = mo * 32 + lmp;
            if (mp >= 208) continue;
            half8 v = {};
            if (mp < MG) v = *(const half8*)&KVh[(size_t)(b * MG + mp) * 1536 + 768 + h * 64 + d0];
#pragma unroll
            for (int j = 0; j < 8; j++) Vt[(d0 + j) * 208 + mp] = v[j];
        }
    }
    __syncthreads();

    const int w = tid >> 6, l = tid & 63;
    const int lm = l & 15, lq = l >> 4;

    int cf[13];
#pragma unroll
    for (int t = 0; t < 13; t++) {
        int col = t * 16 + lm;
        cf[t] = (col < 8) ? -1 : (col >= MG ? -2 : col_frame(col));
    }

    _Float16* Pw = &Ps[(w * 16) * 216];

    for (int t5 = 0; t5 < 5; t5++) {
        const int rb = qc0 + t5 * 64 + w * 16;
        if (rb >= NTOK) break;   // per-wave exit; no barriers below

        floatx4 acc[13] = {};
        const int qrowA = min(rb + lm, NTOK - 1);
        const _Float16* qbase = Qh + (size_t)(b * NTOK + qrowA) * CDIM + h * 64;
#pragma unroll
        for (int ks = 0; ks < 64; ks += 32) {
            half8 aq = *(const half8*)(qbase + ks + lq * 8);
#pragma unroll
            for (int t = 0; t < 13; t++) {
                half8 bk = *(const half8*)&Ks[(t * 16 + lm) * 64 + (((ks >> 3) + lq) ^ (lm & 7)) * 8];
                acc[t] = __builtin_amdgcn_mfma_f32_16x16x32_f16(aq, bk, acc[t], 0, 0, 0);
            }
        }

#pragma unroll
        for (int r = 0; r < 4; r++) {
            int qrow = min(rb + lq * 4 + r, NTOK - 1);
            int rf = qrow / NORI;
            float sv[13];
            float mx = -1e30f;
#pragma unroll
            for (int t = 0; t < 13; t++) {
                float s = acc[t][r] * 0.125f;
                s *= (cf[t] == -1 || cf[t] == rf) ? 1.f : 0.8f;
                if (cf[t] == -2) s = -1e30f;
                sv[t] = s;
                mx = fmaxf(mx, s);
            }
#pragma unroll
            for (int off = 1; off < 16; off <<= 1) mx = fmaxf(mx, __shfl_xor(mx, off, 64));
            float sum = 0.f;
#pragma unroll
            for (int t = 0; t < 13; t++) { sv[t] = __expf(sv[t] - mx); sum += sv[t]; }
#pragma unroll
            for (int off = 1; off < 16; off <<= 1) sum += __shfl_xor(sum, off, 64);
            float inv = 1.f / sum;
#pragma unroll
            for (int t = 0; t < 13; t++) acc[t][r] = sv[t] * inv;
        }

#pragma unroll
        for (int t = 0; t < 13; t++)
#pragma unroll
            for (int r = 0; r < 4; r++)
                Pw[(lq * 4 + r) * 216 + t * 16 + lm] = (_Float16)acc[t][r];

        floatx4 oacc[4] = {};
        const _Float16* prow = &Pw[lm * 216];
#pragma unroll
        for (int ks = 0; ks < 192; ks += 32) {
            half8 ap = *(const half8*)(prow + ks + lq * 8);
#pragma unroll
            for (int t = 0; t < 4; t++) {
                half8 bv = *(const half8*)&Vt[(t * 16 + lm) * 208 + ks + lq * 8];
                oacc[t] = __builtin_amdgcn_mfma_f32_16x16x32_f16(ap, bv, oacc[t], 0, 0, 0);
            }
        }
        {
            typedef _Float16 half4v __attribute__((ext_vector_type(4)));
            half4v ap4 = *(const half4v*)(prow + 192 + lq * 4);
#pragma unroll
            for (int t = 0; t < 4; t++) {
                half4v bv4 = *(const half4v*)&Vt[(t * 16 + lm) * 208 + 192 + lq * 4];
                oacc[t] = __builtin_amdgcn_mfma_f32_16x16x16f16(ap4, bv4, oacc[t], 0, 0, 0);
            }
        }

#pragma unroll
        for (int t = 0; t < 4; t++)
#pragma unroll
            for (int r = 0; r < 4; r++) {
                int qrow = rb + lq * 4 + r;
                if (qrow < NTOK)
                    AOh[(size_t)(b * NTOK + qrow) * CDIM + h * 64 + t * 16 + lm] = (_Float16)oacc[t][r];
            }
    }
}

extern "C" void kernel_launch(void* const* d_in, const int* in_sizes, int n_in,
                              void* d_out, int out_size, void* d_ws, size_t ws_size,
                              hipStream_t stream) {
    const float* x      = (const float*)d_in[0];
    const float* qkv_w  = (const float*)d_in[1];
    const float* proj_w = (const float*)d_in[2];
    const float* proj_b = (const float*)d_in[3];
    float* out = (float*)d_out;

    _Float16* xh     = (_Float16*)d_ws;
    _Float16* qkvwh  = xh + (size_t)TOKENS * CDIM;
    _Float16* projwh = qkvwh + (size_t)3 * CDIM * CDIM;
    _Float16* Qh     = projwh + (size_t)CDIM * CDIM;
    _Float16* KVh    = Qh + (size_t)TOKENS * CDIM;
    _Float16* AOh    = KVh + (size_t)(BATCH * MG) * 1536;

    dim3 blk(256);
    const int ncast = (TOKENS * CDIM + 3 * CDIM * CDIM + CDIM * CDIM) / 8;
    cast_all<<<dim3((ncast + 255) / 256), blk, 0, stream>>>(x, qkv_w, proj_w, xh);

    gemm_qkv<<<dim3(624 + 156), blk, 0, stream>>>(xh, qkvwh, Qh, KVh);

    attn_mfma<<<dim3(BATCH * NHEAD, 5), blk, 0, stream>>>(Qh, KVh, AOh);

    gemm_proj<<<dim3(624), blk, 0, stream>>>(AOh, projwh, proj_b, out);
}